// Round 1
// baseline (980.777 us; speedup 1.0000x reference)
//
#include <hip/hip_runtime.h>
#include <cstdint>
#include <cstddef>

#define NB 4
#define NS 1024
#define ND 512
#define NH 8
#define NLAYER 2
#define NDFF 2048

typedef __attribute__((ext_vector_type(8))) short short8;
typedef __attribute__((ext_vector_type(4))) float f32x4;
typedef __attribute__((ext_vector_type(4))) unsigned short u16x4;
typedef unsigned short u16;
typedef long long ll;

__device__ __forceinline__ float b2f(u16 u) {
  union { unsigned int i; float f; } x; x.i = ((unsigned int)u) << 16; return x.f;
}
__device__ __forceinline__ u16 f2b(float f) {  // RNE fp32 -> bf16
  union { float f; unsigned int i; } x; x.f = f;
  return (u16)((x.i + 0x7FFF + ((x.i >> 16) & 1)) >> 16);
}

struct Zm { int div; ll hi, lo; };   // per-z offset = (z/div)*hi + (z%div)*lo
__device__ __forceinline__ ll zoff(Zm m, int z) {
  return (ll)(z / m.div) * m.hi + (ll)(z % m.div) * m.lo;
}

enum { F_BF16 = 1, F_RELU = 2, F_BCOL = 4, F_BROW = 8, F_RESID = 16 };

// async global->LDS, 16B/lane; LDS dest is wave-uniform base + lane*16 (m104).
// CK-style cast-through-integer for address spaces.
__device__ __forceinline__ void load_lds16(const void* g, void* s) {
  __builtin_amdgcn_global_load_lds(
      (const __attribute__((address_space(1))) void*)(uintptr_t)g,
      (__attribute__((address_space(3))) void*)(uint32_t)(uintptr_t)s, 16, 0, 0);
}

// ---------------------------------------------------------------------------
// BT-form GEMM: C[m,n] = scale * sum_k A[m,k]*B[n,k]  (+bias, relu, resid)
// 128x128 tile, BK=32, 256 threads = 4 waves in 2x2, mfma 16x16x32 bf16.
// ---------------------------------------------------------------------------
__global__ void __launch_bounds__(256)
gemm_bt(const u16* __restrict__ A, int lda, Zm za,
        const u16* __restrict__ Bw, int ldb, Zm zb,
        void* __restrict__ Cv, int ldc, Zm zc,
        const float* __restrict__ bias, Zm zbias,
        const float* __restrict__ resid,
        float scale, int K, int flags)
{
  __shared__ __align__(16) u16 lA[128 * 32];
  __shared__ __align__(16) u16 lB[128 * 32];

  const int z = blockIdx.z;
  A  += zoff(za, z);
  Bw += zoff(zb, z);
  const int bm = blockIdx.y * 128, bn = blockIdx.x * 128;
  const int t = threadIdx.x;
  const int w = t >> 6, lane = t & 63;
  const int wr = w >> 1, wc = w & 1;

  // staging: granule g=16B; issue0 covers rows 0..63, issue1 rows 64..127
  const u16* ga0 = A  + (size_t)(bm + (t >> 2)) * lda + ((t & 3) << 3);
  const u16* ga1 = ga0 + (size_t)64 * lda;
  const u16* gb0 = Bw + (size_t)(bn + (t >> 2)) * ldb + ((t & 3) << 3);
  const u16* gb1 = gb0 + (size_t)64 * ldb;
  char* sa = (char*)lA + (w << 10);   // wave-uniform LDS base
  char* sb = (char*)lB + (w << 10);

  f32x4 acc[4][4];
#pragma unroll
  for (int i = 0; i < 4; ++i)
#pragma unroll
    for (int j = 0; j < 4; ++j) acc[i][j] = (f32x4){0.f, 0.f, 0.f, 0.f};

  const int fr = lane & 15;            // fragment row (m or n)
  const int kg = (lane >> 4) << 3;     // k offset within BK=32

  for (int k0 = 0; k0 < K; k0 += 32) {
    load_lds16(ga0 + k0, sa);
    load_lds16(ga1 + k0, sa + 4096);
    load_lds16(gb0 + k0, sb);
    load_lds16(gb1 + k0, sb + 4096);
    __syncthreads();                   // compiler drains vmcnt before barrier
    short8 af[4], bf[4];
#pragma unroll
    for (int mi = 0; mi < 4; ++mi)
      af[mi] = *(const short8*)(lA + (wr * 64 + mi * 16 + fr) * 32 + kg);
#pragma unroll
    for (int ni = 0; ni < 4; ++ni)
      bf[ni] = *(const short8*)(lB + (wc * 64 + ni * 16 + fr) * 32 + kg);
#pragma unroll
    for (int mi = 0; mi < 4; ++mi)
#pragma unroll
      for (int ni = 0; ni < 4; ++ni)
        asm volatile("v_mfma_f32_16x16x32_bf16 %0, %1, %2, %0"
                     : "+v"(acc[mi][ni]) : "v"(af[mi]), "v"(bf[ni]));
    __syncthreads();
  }

  asm volatile("s_nop 7\n\ts_nop 7" ::: "memory");  // MFMA->VALU read hazard guard

  const ll co = zoff(zc, z);
  const float* bz = (flags & (F_BCOL | F_BROW)) ? bias + zoff(zbias, z) : nullptr;
  const int r0 = (lane >> 4) << 2;
  const int c0 = lane & 15;
#pragma unroll
  for (int mi = 0; mi < 4; ++mi) {
#pragma unroll
    for (int ni = 0; ni < 4; ++ni) {
#pragma unroll
      for (int r = 0; r < 4; ++r) {
        const int grow = bm + wr * 64 + mi * 16 + r0 + r;   // C/D row (m89)
        const int gcol = bn + wc * 64 + ni * 16 + c0;       // C/D col
        float v = acc[mi][ni][r] * scale;
        if (flags & F_BCOL) v += bz[gcol];
        if (flags & F_BROW) v += bz[grow];
        if (flags & F_RELU) v = fmaxf(v, 0.f);
        if (flags & F_RESID) v += resid[(size_t)grow * ldc + gcol];
        const ll idx = co + (ll)grow * ldc + gcol;
        if (flags & F_BF16) ((u16*)Cv)[idx] = f2b(v);
        else                ((float*)Cv)[idx] = v;
      }
    }
  }
}

// in-place softmax over rows of 1024 bf16
__global__ void __launch_bounds__(256)
softmax_rows(u16* __restrict__ sc)
{
  const int row = blockIdx.x;
  u16* p = sc + (size_t)row * 1024;
  const int t = threadIdx.x;
  const int w = t >> 6, lane = t & 63;
  u16x4 u = *(const u16x4*)(p + t * 4);
  float v0 = b2f(u.x), v1 = b2f(u.y), v2 = b2f(u.z), v3 = b2f(u.w);
  float mx = fmaxf(fmaxf(v0, v1), fmaxf(v2, v3));
#pragma unroll
  for (int o = 32; o >= 1; o >>= 1) mx = fmaxf(mx, __shfl_xor(mx, o));
  __shared__ float red[8];
  if (lane == 0) red[w] = mx;
  __syncthreads();
  mx = fmaxf(fmaxf(red[0], red[1]), fmaxf(red[2], red[3]));
  float e0 = __expf(v0 - mx), e1 = __expf(v1 - mx);
  float e2 = __expf(v2 - mx), e3 = __expf(v3 - mx);
  float s = e0 + e1 + e2 + e3;
#pragma unroll
  for (int o = 32; o >= 1; o >>= 1) s += __shfl_xor(s, o);
  if (lane == 0) red[4 + w] = s;
  __syncthreads();
  s = red[4] + red[5] + red[6] + red[7];
  const float inv = 1.f / s;
  u16x4 o4;
  o4.x = f2b(e0 * inv); o4.y = f2b(e1 * inv);
  o4.z = f2b(e2 * inv); o4.w = f2b(e3 * inv);
  *(u16x4*)(p + t * 4) = o4;
}

// LayerNorm over rows of 512 fp32; writes fp32 (residual stream) + bf16 copy
__global__ void __launch_bounds__(64)
ln_rows(const float* __restrict__ in, const float* __restrict__ g,
        const float* __restrict__ be, float* __restrict__ xout,
        u16* __restrict__ xbout)
{
  const int row = blockIdx.x;
  const float* p = in + (size_t)row * ND;
  const int t = threadIdx.x;
  float v[8];
  *(f32x4*)(v)     = *(const f32x4*)(p + t * 8);
  *(f32x4*)(v + 4) = *(const f32x4*)(p + t * 8 + 4);
  float s = 0.f, q = 0.f;
#pragma unroll
  for (int j = 0; j < 8; ++j) { s += v[j]; q += v[j] * v[j]; }
#pragma unroll
  for (int o = 32; o >= 1; o >>= 1) { s += __shfl_xor(s, o); q += __shfl_xor(q, o); }
  const float mean = s * (1.f / ND);
  const float var  = q * (1.f / ND) - mean * mean;
  const float inv  = 1.f / sqrtf(var + 1e-5f);
#pragma unroll
  for (int j = 0; j < 8; ++j) {
    const int c = t * 8 + j;
    const float y = (v[j] - mean) * inv * g[c] + be[c];
    xout[(size_t)row * ND + c] = y;
    xbout[(size_t)row * ND + c] = f2b(y);
  }
}

__global__ void __launch_bounds__(256)
f32_to_bf16(const float* __restrict__ in, u16* __restrict__ out, ll n)
{
  const ll i = ((ll)blockIdx.x * 256 + threadIdx.x) * 4;
  if (i >= n) return;
  f32x4 v = *(const f32x4*)(in + i);
  u16x4 o;
  o.x = f2b(v.x); o.y = f2b(v.y); o.z = f2b(v.z); o.w = f2b(v.w);
  *(u16x4*)(out + i) = o;
}

// ---------------------------------------------------------------------------
extern "C" void kernel_launch(void* const* d_in, const int* in_sizes, int n_in,
                              void* d_out, int out_size, void* d_ws, size_t ws_size,
                              hipStream_t stream)
{
  (void)in_sizes; (void)n_in; (void)out_size; (void)ws_size;
  const float* x_in = (const float*)d_in[0];
  const float* Wq = (const float*)d_in[1];  const float* bq = (const float*)d_in[2];
  const float* Wk = (const float*)d_in[3];  const float* bk = (const float*)d_in[4];
  const float* Wv = (const float*)d_in[5];  const float* bv = (const float*)d_in[6];
  const float* Wo = (const float*)d_in[7];  const float* bo = (const float*)d_in[8];
  const float* W1 = (const float*)d_in[9];  const float* b1 = (const float*)d_in[10];
  const float* W2 = (const float*)d_in[11]; const float* b2 = (const float*)d_in[12];
  const float* ln1g = (const float*)d_in[13]; const float* ln1b = (const float*)d_in[14];
  const float* ln2g = (const float*)d_in[15]; const float* ln2b = (const float*)d_in[16];

  char* p = (char*)d_ws;
  auto alloc = [&](ll bytes) { char* r = p; p += (bytes + 255) & ~(ll)255; return r; };
  const ll nWq = (ll)NLAYER * NH * ND * ND;     // 4.19M (per q/k/v tensor)
  const ll nWo = (ll)NLAYER * ND * NH * ND;
  const ll nW1 = (ll)NLAYER * NDFF * ND;
  const ll nX  = (ll)NB * NS * ND;

  u16* wq_b = (u16*)alloc(nWq * 2);
  u16* wk_b = (u16*)alloc(nWq * 2);
  u16* wv_b = (u16*)alloc(nWq * 2);
  u16* wo_b = (u16*)alloc(nWo * 2);
  u16* w1_b = (u16*)alloc(nW1 * 2);
  u16* w2_b = (u16*)alloc(nW1 * 2);
  u16* xb   = (u16*)alloc(nX * 2);
  u16* qb   = (u16*)alloc((ll)NH * NB * NS * ND * 2);  // [h][b*s][e]
  u16* kb   = (u16*)alloc((ll)NH * NB * NS * ND * 2);
  u16* vT   = (u16*)alloc((ll)NH * NB * ND * NS * 2);  // [h][b][e][t]
  u16* scb  = (u16*)alloc((ll)NB * NH * NS * NS * 2);  // [h*4+b][s][t]
  float* tmp = (float*)alloc(nX * 4);
  u16* cat = kb;   // overlay: k dead after scores
  u16* ffh = qb;   // overlay: q dead after scores

  auto cvt = [&](const float* src, u16* dst, ll n) {
    f32_to_bf16<<<dim3((unsigned)((n / 4 + 255) / 256)), 256, 0, stream>>>(src, dst, n);
  };
  cvt(Wq, wq_b, nWq); cvt(Wk, wk_b, nWq); cvt(Wv, wv_b, nWq);
  cvt(Wo, wo_b, nWo); cvt(W1, w1_b, nW1); cvt(W2, w2_b, nW1);
  cvt(x_in, xb, nX);

  float* xf = (float*)d_out;           // fp32 residual stream lives in d_out
  const Zm Z0{1, 0, 0};

  for (int i = 0; i < NLAYER; ++i) {
    const float* resid1 = (i == 0) ? x_in : xf;
    const ll woff = (ll)i * NH * ND * ND;

    // q,k projections: z=h, C[h][b*s][e]
    gemm_bt<<<dim3(ND/128, (NB*NS)/128, NH), 256, 0, stream>>>(
        xb, ND, Z0, wq_b + woff, ND, Zm{1, (ll)ND * ND, 0},
        qb, ND, Zm{1, (ll)NB * NS * ND, 0},
        bq + (ll)i * NH * ND, Zm{1, ND, 0}, nullptr, 1.f, ND, F_BF16 | F_BCOL);
    gemm_bt<<<dim3(ND/128, (NB*NS)/128, NH), 256, 0, stream>>>(
        xb, ND, Z0, wk_b + woff, ND, Zm{1, (ll)ND * ND, 0},
        kb, ND, Zm{1, (ll)NB * NS * ND, 0},
        bk + (ll)i * NH * ND, Zm{1, ND, 0}, nullptr, 1.f, ND, F_BF16 | F_BCOL);

    // vT projection (operands swapped -> transposed out): z=h*4+b, C[e][t]
    gemm_bt<<<dim3(NS/128, ND/128, NH*NB), 256, 0, stream>>>(
        wv_b + woff, ND, Zm{NB, (ll)ND * ND, 0},
        xb, ND, Zm{NB, 0, (ll)NS * ND},
        vT, NS, Zm{1, (ll)ND * NS, 0},
        bv + (ll)i * NH * ND, Zm{NB, ND, 0}, nullptr, 1.f, ND, F_BF16 | F_BROW);

    // scores = q k^T / 8 : z=h*4+b
    gemm_bt<<<dim3(NS/128, NS/128, NH*NB), 256, 0, stream>>>(
        qb, ND, Zm{NB, (ll)NB * NS * ND, (ll)NS * ND},
        kb, ND, Zm{NB, (ll)NB * NS * ND, (ll)NS * ND},
        scb, NS, Zm{1, (ll)NS * NS, 0},
        nullptr, Z0, nullptr, 0.125f, ND, F_BF16);

    softmax_rows<<<dim3(NB * NH * NS), 256, 0, stream>>>(scb);

    // heads = attn @ v : C -> cat[b][s][h*512+e]
    gemm_bt<<<dim3(ND/128, NS/128, NH*NB), 256, 0, stream>>>(
        scb, NS, Zm{1, (ll)NS * NS, 0},
        vT, NS, Zm{1, (ll)ND * NS, 0},
        cat, NH * ND, Zm{NB, (ll)ND, (ll)NS * NH * ND},
        nullptr, Z0, nullptr, 1.f, NS, F_BF16);

    // mha_out = cat @ Wo^T + bo + resid -> tmp (fp32)
    gemm_bt<<<dim3(ND/128, (NB*NS)/128, 1), 256, 0, stream>>>(
        cat, NH * ND, Z0,
        wo_b + (ll)i * ND * NH * ND, NH * ND, Z0,
        tmp, ND, Z0,
        bo + (ll)i * ND, Z0, resid1, 1.f, NH * ND, F_BCOL | F_RESID);

    ln_rows<<<dim3(NB * NS), 64, 0, stream>>>(
        tmp, ln1g + (ll)i * ND, ln1b + (ll)i * ND, xf, xb);

    // ffh = relu(x @ W1^T + b1)  (bf16)
    gemm_bt<<<dim3(NDFF/128, (NB*NS)/128, 1), 256, 0, stream>>>(
        xb, ND, Z0,
        w1_b + (ll)i * NDFF * ND, ND, Z0,
        ffh, NDFF, Z0,
        b1 + (ll)i * NDFF, Z0, nullptr, 1.f, ND, F_BF16 | F_BCOL | F_RELU);

    // ff = ffh @ W2^T + b2 + x -> tmp (fp32)
    gemm_bt<<<dim3(ND/128, (NB*NS)/128, 1), 256, 0, stream>>>(
        ffh, NDFF, Z0,
        w2_b + (ll)i * ND * NDFF, NDFF, Z0,
        tmp, ND, Z0,
        b2 + (ll)i * ND, Z0, xf, 1.f, NDFF, F_BCOL | F_RESID);

    ln_rows<<<dim3(NB * NS), 64, 0, stream>>>(
        tmp, ln2g + (ll)i * ND, ln2b + (ll)i * ND, xf, xb);
  }
}

// Round 2
// 800.391 us; speedup vs baseline: 1.2254x; 1.2254x over previous
//
#include <hip/hip_runtime.h>
#include <cstdint>
#include <cstddef>

#define NB 4
#define NS 1024
#define ND 512
#define NH 8
#define NLAYER 2
#define NDFF 2048

typedef __attribute__((ext_vector_type(8))) short short8;
typedef __attribute__((ext_vector_type(4))) float f32x4;
typedef __attribute__((ext_vector_type(4))) unsigned short u16x4;
typedef unsigned short u16;
typedef long long ll;

__device__ __forceinline__ float b2f(u16 u) {
  union { unsigned int i; float f; } x; x.i = ((unsigned int)u) << 16; return x.f;
}
__device__ __forceinline__ u16 f2b(float f) {  // RNE fp32 -> bf16
  union { float f; unsigned int i; } x; x.f = f;
  return (u16)((x.i + 0x7FFF + ((x.i >> 16) & 1)) >> 16);
}

struct Zm { int div; ll hi, lo; };   // per-z offset = (z/div)*hi + (z%div)*lo
__device__ __forceinline__ ll zoff(Zm m, int z) {
  return (ll)(z / m.div) * m.hi + (ll)(z % m.div) * m.lo;
}

enum { F_BF16 = 1, F_RELU = 2, F_BCOL = 4, F_BROW = 8, F_RESID = 16 };

// async global->LDS, 16B/lane; LDS dest is wave-uniform base + lane*16 (m104).
__device__ __forceinline__ void load_lds16(const void* g, void* s) {
  __builtin_amdgcn_global_load_lds(
      (const __attribute__((address_space(1))) void*)(uintptr_t)g,
      (__attribute__((address_space(3))) void*)(uint32_t)(uintptr_t)s, 16, 0, 0);
}

// ---------------------------------------------------------------------------
// BT-form GEMM: C[m,n] = scale * sum_k A[m,k]*B[n,k]  (+bias, relu, resid)
// 128x128 tile, BK=32, 256 threads = 4 waves in 2x2, mfma 16x16x32 bf16.
// flags==0 -> raw fp32 write (split-K partial path).
// ---------------------------------------------------------------------------
__global__ void __launch_bounds__(256)
gemm_bt(const u16* __restrict__ A, int lda, Zm za,
        const u16* __restrict__ Bw, int ldb, Zm zb,
        void* __restrict__ Cv, int ldc, Zm zc,
        const float* __restrict__ bias, Zm zbias,
        const float* __restrict__ resid,
        float scale, int K, int flags)
{
  __shared__ __align__(16) u16 lA[128 * 32];
  __shared__ __align__(16) u16 lB[128 * 32];

  const int z = blockIdx.z;
  A  += zoff(za, z);
  Bw += zoff(zb, z);
  const int bm = blockIdx.y * 128, bn = blockIdx.x * 128;
  const int t = threadIdx.x;
  const int w = t >> 6, lane = t & 63;
  const int wr = w >> 1, wc = w & 1;

  const u16* ga0 = A  + (size_t)(bm + (t >> 2)) * lda + ((t & 3) << 3);
  const u16* ga1 = ga0 + (size_t)64 * lda;
  const u16* gb0 = Bw + (size_t)(bn + (t >> 2)) * ldb + ((t & 3) << 3);
  const u16* gb1 = gb0 + (size_t)64 * ldb;
  char* sa = (char*)lA + (w << 10);   // wave-uniform LDS base
  char* sb = (char*)lB + (w << 10);

  f32x4 acc[4][4];
#pragma unroll
  for (int i = 0; i < 4; ++i)
#pragma unroll
    for (int j = 0; j < 4; ++j) acc[i][j] = (f32x4){0.f, 0.f, 0.f, 0.f};

  const int fr = lane & 15;            // fragment row (m or n)
  const int kg = (lane >> 4) << 3;     // k offset within BK=32

  for (int k0 = 0; k0 < K; k0 += 32) {
    load_lds16(ga0 + k0, sa);
    load_lds16(ga1 + k0, sa + 4096);
    load_lds16(gb0 + k0, sb);
    load_lds16(gb1 + k0, sb + 4096);
    __syncthreads();
    short8 af[4], bf[4];
#pragma unroll
    for (int mi = 0; mi < 4; ++mi)
      af[mi] = *(const short8*)(lA + (wr * 64 + mi * 16 + fr) * 32 + kg);
#pragma unroll
    for (int ni = 0; ni < 4; ++ni)
      bf[ni] = *(const short8*)(lB + (wc * 64 + ni * 16 + fr) * 32 + kg);
#pragma unroll
    for (int mi = 0; mi < 4; ++mi)
#pragma unroll
      for (int ni = 0; ni < 4; ++ni)
        asm volatile("v_mfma_f32_16x16x32_bf16 %0, %1, %2, %0"
                     : "+v"(acc[mi][ni]) : "v"(af[mi]), "v"(bf[ni]));
    __syncthreads();
  }

  asm volatile("s_nop 7\n\ts_nop 7" ::: "memory");  // MFMA->VALU hazard guard

  const ll co = zoff(zc, z);
  const float* bz = (flags & (F_BCOL | F_BROW)) ? bias + zoff(zbias, z) : nullptr;
  const int r0 = (lane >> 4) << 2;
  const int c0 = lane & 15;
#pragma unroll
  for (int mi = 0; mi < 4; ++mi) {
#pragma unroll
    for (int ni = 0; ni < 4; ++ni) {
#pragma unroll
      for (int r = 0; r < 4; ++r) {
        const int grow = bm + wr * 64 + mi * 16 + r0 + r;   // C/D row (m89)
        const int gcol = bn + wc * 64 + ni * 16 + c0;       // C/D col
        float v = acc[mi][ni][r] * scale;
        if (flags & F_BCOL) v += bz[gcol];
        if (flags & F_BROW) v += bz[grow];
        if (flags & F_RELU) v = fmaxf(v, 0.f);
        if (flags & F_RESID) v += resid[(size_t)grow * ldc + gcol];
        const ll idx = co + (ll)grow * ldc + gcol;
        if (flags & F_BF16) ((u16*)Cv)[idx] = f2b(v);
        else                ((float*)Cv)[idx] = v;
      }
    }
  }
}

// in-place softmax over rows of 1024 bf16
__global__ void __launch_bounds__(256)
softmax_rows(u16* __restrict__ sc)
{
  const int row = blockIdx.x;
  u16* p = sc + (size_t)row * 1024;
  const int t = threadIdx.x;
  const int w = t >> 6, lane = t & 63;
  u16x4 u = *(const u16x4*)(p + t * 4);
  float v0 = b2f(u.x), v1 = b2f(u.y), v2 = b2f(u.z), v3 = b2f(u.w);
  float mx = fmaxf(fmaxf(v0, v1), fmaxf(v2, v3));
#pragma unroll
  for (int o = 32; o >= 1; o >>= 1) mx = fmaxf(mx, __shfl_xor(mx, o));
  __shared__ float red[8];
  if (lane == 0) red[w] = mx;
  __syncthreads();
  mx = fmaxf(fmaxf(red[0], red[1]), fmaxf(red[2], red[3]));
  float e0 = __expf(v0 - mx), e1 = __expf(v1 - mx);
  float e2 = __expf(v2 - mx), e3 = __expf(v3 - mx);
  float s = e0 + e1 + e2 + e3;
#pragma unroll
  for (int o = 32; o >= 1; o >>= 1) s += __shfl_xor(s, o);
  if (lane == 0) red[4 + w] = s;
  __syncthreads();
  s = red[4] + red[5] + red[6] + red[7];
  const float inv = 1.f / s;
  u16x4 o4;
  o4.x = f2b(e0 * inv); o4.y = f2b(e1 * inv);
  o4.z = f2b(e2 * inv); o4.w = f2b(e3 * inv);
  *(u16x4*)(p + t * 4) = o4;
}

// fused split-K reduce + bias + residual + LayerNorm (rows of 512)
// one wave per row; writes fp32 residual stream + bf16 copy
__global__ void __launch_bounds__(64)
ln_red(const float* __restrict__ parts, int np, ll pstride,
       const float* __restrict__ bias, const float* __restrict__ resid,
       const float* __restrict__ g, const float* __restrict__ be,
       float* __restrict__ xout, u16* __restrict__ xbout)
{
  const int row = blockIdx.x;
  const int t = threadIdx.x;
  const ll base = (ll)row * ND + t * 8;
  float v[8];
  *(f32x4*)(v)     = *(const f32x4*)(resid + base);
  *(f32x4*)(v + 4) = *(const f32x4*)(resid + base + 4);
#pragma unroll
  for (int j = 0; j < 8; ++j) v[j] += bias[t * 8 + j];
  for (int pIdx = 0; pIdx < np; ++pIdx) {
    const float* pp = parts + pIdx * pstride + base;
    f32x4 a0 = *(const f32x4*)(pp);
    f32x4 a1 = *(const f32x4*)(pp + 4);
    v[0] += a0.x; v[1] += a0.y; v[2] += a0.z; v[3] += a0.w;
    v[4] += a1.x; v[5] += a1.y; v[6] += a1.z; v[7] += a1.w;
  }
  float s = 0.f, q = 0.f;
#pragma unroll
  for (int j = 0; j < 8; ++j) { s += v[j]; q += v[j] * v[j]; }
#pragma unroll
  for (int o = 32; o >= 1; o >>= 1) { s += __shfl_xor(s, o); q += __shfl_xor(q, o); }
  const float mean = s * (1.f / ND);
  const float var  = q * (1.f / ND) - mean * mean;
  const float inv  = 1.f / sqrtf(var + 1e-5f);
#pragma unroll
  for (int j = 0; j < 8; ++j) {
    const int c = t * 8 + j;
    const float y = (v[j] - mean) * inv * g[c] + be[c];
    xout[(ll)row * ND + c] = y;
    xbout[(ll)row * ND + c] = f2b(y);
  }
}

struct CvtJobs { const float* src[6]; u16* dst[6]; ll n[6]; };

__global__ void __launch_bounds__(256)
cvt6(CvtJobs j)
{
  const int z = blockIdx.y;
  const ll i = ((ll)blockIdx.x * 256 + threadIdx.x) * 4;
  if (i >= j.n[z]) return;
  f32x4 v = *(const f32x4*)(j.src[z] + i);
  u16x4 o;
  o.x = f2b(v.x); o.y = f2b(v.y); o.z = f2b(v.z); o.w = f2b(v.w);
  *(u16x4*)(j.dst[z] + i) = o;
}

__global__ void __launch_bounds__(256)
f32_to_bf16(const float* __restrict__ in, u16* __restrict__ out, ll n)
{
  const ll i = ((ll)blockIdx.x * 256 + threadIdx.x) * 4;
  if (i >= n) return;
  f32x4 v = *(const f32x4*)(in + i);
  u16x4 o;
  o.x = f2b(v.x); o.y = f2b(v.y); o.z = f2b(v.z); o.w = f2b(v.w);
  *(u16x4*)(out + i) = o;
}

// ---------------------------------------------------------------------------
extern "C" void kernel_launch(void* const* d_in, const int* in_sizes, int n_in,
                              void* d_out, int out_size, void* d_ws, size_t ws_size,
                              hipStream_t stream)
{
  (void)in_sizes; (void)n_in; (void)out_size; (void)ws_size;
  const float* x_in = (const float*)d_in[0];
  const float* Wq = (const float*)d_in[1];  const float* bq = (const float*)d_in[2];
  const float* Wk = (const float*)d_in[3];  const float* bk = (const float*)d_in[4];
  const float* Wv = (const float*)d_in[5];  const float* bv = (const float*)d_in[6];
  const float* Wo = (const float*)d_in[7];  const float* bo = (const float*)d_in[8];
  const float* W1 = (const float*)d_in[9];  const float* b1 = (const float*)d_in[10];
  const float* W2 = (const float*)d_in[11]; const float* b2 = (const float*)d_in[12];
  const float* ln1g = (const float*)d_in[13]; const float* ln1b = (const float*)d_in[14];
  const float* ln2g = (const float*)d_in[15]; const float* ln2b = (const float*)d_in[16];

  char* p = (char*)d_ws;
  auto alloc = [&](ll bytes) { char* r = p; p += (bytes + 255) & ~(ll)255; return r; };
  const ll nWq = (ll)NLAYER * NH * ND * ND;
  const ll nWo = (ll)NLAYER * ND * NH * ND;
  const ll nW1 = (ll)NLAYER * NDFF * ND;
  const ll nX  = (ll)NB * NS * ND;

  u16* wq_b = (u16*)alloc(nWq * 2);
  u16* wk_b = (u16*)alloc(nWq * 2);
  u16* wv_b = (u16*)alloc(nWq * 2);
  u16* wo_b = (u16*)alloc(nWo * 2);
  u16* w1_b = (u16*)alloc(nW1 * 2);
  u16* w2_b = (u16*)alloc(nW1 * 2);
  u16* xb   = (u16*)alloc(nX * 2);
  u16* qb   = (u16*)alloc((ll)NH * NB * NS * ND * 2);  // [h][b*s][e]
  u16* kb   = (u16*)alloc((ll)NH * NB * NS * ND * 2);
  u16* vT   = (u16*)alloc((ll)NH * NB * ND * NS * 2);  // [h][b][e][t]
  u16* scb  = (u16*)alloc((ll)NB * NH * NS * NS * 2);  // [h*4+b][s][t]; overlaid by split-K partials
  u16* cat = kb;                 // overlay: k dead after scores
  u16* ffh = qb;                 // overlay: q dead after scores
  float* parts = (float*)scb;    // overlay: scb dead after heads GEMM

  CvtJobs cj;
  cj.src[0] = Wq; cj.dst[0] = wq_b; cj.n[0] = nWq;
  cj.src[1] = Wk; cj.dst[1] = wk_b; cj.n[1] = nWq;
  cj.src[2] = Wv; cj.dst[2] = wv_b; cj.n[2] = nWq;
  cj.src[3] = Wo; cj.dst[3] = wo_b; cj.n[3] = nWo;
  cj.src[4] = W1; cj.dst[4] = w1_b; cj.n[4] = nW1;
  cj.src[5] = W2; cj.dst[5] = w2_b; cj.n[5] = nW1;
  cvt6<<<dim3((unsigned)((nWq / 4 + 255) / 256), 6), 256, 0, stream>>>(cj);
  f32_to_bf16<<<dim3((unsigned)((nX / 4 + 255) / 256)), 256, 0, stream>>>(x_in, xb, nX);

  float* xf = (float*)d_out;           // fp32 residual stream lives in d_out
  const Zm Z0{1, 0, 0};
  const ll PSTR = (ll)NB * NS * ND;    // split-K partial stride (elements)

  for (int i = 0; i < NLAYER; ++i) {
    const float* resid1 = (i == 0) ? x_in : xf;
    const ll woff = (ll)i * NH * ND * ND;

    // q,k projections: z=h, C[h][b*s][e]
    gemm_bt<<<dim3(ND/128, (NB*NS)/128, NH), 256, 0, stream>>>(
        xb, ND, Z0, wq_b + woff, ND, Zm{1, (ll)ND * ND, 0},
        qb, ND, Zm{1, (ll)NB * NS * ND, 0},
        bq + (ll)i * NH * ND, Zm{1, ND, 0}, nullptr, 1.f, ND, F_BF16 | F_BCOL);
    gemm_bt<<<dim3(ND/128, (NB*NS)/128, NH), 256, 0, stream>>>(
        xb, ND, Z0, wk_b + woff, ND, Zm{1, (ll)ND * ND, 0},
        kb, ND, Zm{1, (ll)NB * NS * ND, 0},
        bk + (ll)i * NH * ND, Zm{1, ND, 0}, nullptr, 1.f, ND, F_BF16 | F_BCOL);

    // vT projection (operands swapped -> transposed out): z=h*4+b, C[e][t]
    gemm_bt<<<dim3(NS/128, ND/128, NH*NB), 256, 0, stream>>>(
        wv_b + woff, ND, Zm{NB, (ll)ND * ND, 0},
        xb, ND, Zm{NB, 0, (ll)NS * ND},
        vT, NS, Zm{1, (ll)ND * NS, 0},
        bv + (ll)i * NH * ND, Zm{NB, ND, 0}, nullptr, 1.f, ND, F_BF16 | F_BROW);

    // scores = q k^T / 8 : z=h*4+b
    gemm_bt<<<dim3(NS/128, NS/128, NH*NB), 256, 0, stream>>>(
        qb, ND, Zm{NB, (ll)NB * NS * ND, (ll)NS * ND},
        kb, ND, Zm{NB, (ll)NB * NS * ND, (ll)NS * ND},
        scb, NS, Zm{1, (ll)NS * NS, 0},
        nullptr, Z0, nullptr, 0.125f, ND, F_BF16);

    softmax_rows<<<dim3(NB * NH * NS), 256, 0, stream>>>(scb);

    // heads = attn @ v : C -> cat[b][s][h*512+e]
    gemm_bt<<<dim3(ND/128, NS/128, NH*NB), 256, 0, stream>>>(
        scb, NS, Zm{1, (ll)NS * NS, 0},
        vT, NS, Zm{1, (ll)ND * NS, 0},
        cat, NH * ND, Zm{NB, (ll)ND, (ll)NS * NH * ND},
        nullptr, Z0, nullptr, 1.f, NS, F_BF16);

    // mha_out partials: split-K over K=4096 into 8 chunks of 512 (z dim)
    gemm_bt<<<dim3(ND/128, (NB*NS)/128, 8), 256, 0, stream>>>(
        cat, NH * ND, Zm{1, 512, 0},
        wo_b + (ll)i * ND * NH * ND, NH * ND, Zm{1, 512, 0},
        parts, ND, Zm{1, PSTR, 0},
        nullptr, Z0, nullptr, 1.f, 512, 0);

    // LN1 = LayerNorm(resid + bo + sum parts)
    ln_red<<<dim3(NB * NS), 64, 0, stream>>>(
        parts, 8, PSTR, bo + (ll)i * ND, resid1,
        ln1g + (ll)i * ND, ln1b + (ll)i * ND, xf, xb);

    // ffh = relu(x @ W1^T + b1)  (bf16)
    gemm_bt<<<dim3(NDFF/128, (NB*NS)/128, 1), 256, 0, stream>>>(
        xb, ND, Z0,
        w1_b + (ll)i * NDFF * ND, ND, Z0,
        ffh, NDFF, Z0,
        b1 + (ll)i * NDFF, Z0, nullptr, 1.f, ND, F_BF16 | F_BCOL | F_RELU);

    // ff partials: split-K over K=2048 into 4 chunks of 512
    gemm_bt<<<dim3(ND/128, (NB*NS)/128, 4), 256, 0, stream>>>(
        ffh, NDFF, Zm{1, 512, 0},
        w2_b + (ll)i * ND * NDFF, NDFF, Zm{1, 512, 0},
        parts, ND, Zm{1, PSTR, 0},
        nullptr, Z0, nullptr, 1.f, 512, 0);

    // LN2 = LayerNorm(x + b2 + sum parts)
    ln_red<<<dim3(NB * NS), 64, 0, stream>>>(
        parts, 4, PSTR, b2 + (ll)i * ND, xf,
        ln2g + (ll)i * ND, ln2b + (ll)i * ND, xf, xb);
  }
}

// Round 3
// 681.620 us; speedup vs baseline: 1.4389x; 1.1742x over previous
//
#include <hip/hip_runtime.h>
#include <cstdint>
#include <cstddef>

#define NB 4
#define NS 1024
#define ND 512
#define NH 8
#define NLAYER 2
#define NDFF 2048

typedef __attribute__((ext_vector_type(8))) short short8;
typedef __attribute__((ext_vector_type(4))) float f32x4;
typedef __attribute__((ext_vector_type(4))) unsigned short u16x4;
typedef unsigned short u16;
typedef long long ll;

__device__ __forceinline__ float b2f(u16 u) {
  union { unsigned int i; float f; } x; x.i = ((unsigned int)u) << 16; return x.f;
}
__device__ __forceinline__ u16 f2b(float f) {  // RNE fp32 -> bf16
  union { float f; unsigned int i; } x; x.f = f;
  return (u16)((x.i + 0x7FFF + ((x.i >> 16) & 1)) >> 16);
}

struct Zm { int div; ll hi, lo; };   // per-z offset = (z/div)*hi + (z%div)*lo
__device__ __forceinline__ ll zoff(Zm m, int z) {
  return (ll)(z / m.div) * m.hi + (ll)(z % m.div) * m.lo;
}

enum { F_BF16 = 1, F_RELU = 2, F_BCOL = 4, F_BROW = 8, F_RESID = 16 };

// async global->LDS, 16B/lane; LDS dest is wave-uniform base + lane*16 (m104).
__device__ __forceinline__ void load_lds16(const void* g, void* s) {
  __builtin_amdgcn_global_load_lds(
      (const __attribute__((address_space(1))) void*)(uintptr_t)g,
      (__attribute__((address_space(3))) void*)(uint32_t)(uintptr_t)s, 16, 0, 0);
}

// ---------------------------------------------------------------------------
// BT-form GEMM: C[m,n] = scale * sum_k A[m,k]*B[n,k]  (+bias, relu, resid)
// 128x128 tile, BK=32, 4 waves 2x2, mfma 16x16x32 bf16.
// T3-minimum 2-phase pipeline: dbuf LDS, prefetch tile t+1 before computing t,
// ONE barrier per K-step. T1 XCD-chunked swizzle. z>=zsplit selects Bw2/bias2.
// flags==0 -> raw fp32 write (split-K partial path).
// ---------------------------------------------------------------------------
__global__ void __launch_bounds__(256)
gemm_bt(const u16* __restrict__ A, int lda, Zm za,
        const u16* __restrict__ Bw, int ldb, Zm zb,
        const u16* __restrict__ Bw2, const float* __restrict__ bias2, int zsplit,
        void* __restrict__ Cv, int ldc, Zm zc,
        const float* __restrict__ bias, Zm zbias,
        const float* __restrict__ resid,
        float scale, int K, int flags)
{
  __shared__ __align__(16) char smem[2][16384];   // [buf][A:0..8191 | B:8192..]

  // T1: XCD-chunked block swizzle (bijective when nwg%8==0)
  const int gx = gridDim.x, gy = gridDim.y;
  int id = (blockIdx.z * gy + blockIdx.y) * gx + blockIdx.x;
  const int nwg = gx * gy * (int)gridDim.z;
  if ((nwg & 7) == 0) id = (id & 7) * (nwg >> 3) + (id >> 3);
  const int bx = id % gx;
  const int rest = id / gx;
  const int by = rest % gy;
  const int z0 = rest / gy;

  int zB = z0;
  const u16* Bsel = Bw;
  const float* bsel = bias;
  if (z0 >= zsplit) { Bsel = Bw2; bsel = bias2; zB = z0 - zsplit; }

  A    += zoff(za, z0);
  Bsel += zoff(zb, zB);

  const int bm = by * 128, bn = bx * 128;
  const int t = threadIdx.x;
  const int w = t >> 6, lane = t & 63;
  const int wr = w >> 1, wc = w & 1;

  const u16* ga0 = A    + (size_t)(bm + (t >> 2)) * lda + ((t & 3) << 3);
  const u16* ga1 = ga0 + (size_t)64 * lda;
  const u16* gb0 = Bsel + (size_t)(bn + (t >> 2)) * ldb + ((t & 3) << 3);
  const u16* gb1 = gb0 + (size_t)64 * ldb;

  auto STAGE = [&](int sel, int kt) {
    const int k0 = kt << 5;
    char* sa = smem[sel] + (w << 10);
    char* sb = smem[sel] + 8192 + (w << 10);
    load_lds16(ga0 + k0, sa);
    load_lds16(ga1 + k0, sa + 4096);
    load_lds16(gb0 + k0, sb);
    load_lds16(gb1 + k0, sb + 4096);
  };

  f32x4 acc[4][4];
#pragma unroll
  for (int i = 0; i < 4; ++i)
#pragma unroll
    for (int j = 0; j < 4; ++j) acc[i][j] = (f32x4){0.f, 0.f, 0.f, 0.f};

  const int fr = lane & 15;            // fragment row (m or n)
  const int kg = (lane >> 4) << 3;     // k offset within BK=32

  const int nt = K >> 5;
  STAGE(0, 0);
  __syncthreads();
  int cur = 0;
  for (int kt = 0; kt < nt; ++kt) {
    if (kt + 1 < nt) STAGE(cur ^ 1, kt + 1);   // prefetch flies under compute
    const u16* la = (const u16*)smem[cur];
    const u16* lb = (const u16*)(smem[cur] + 8192);
    short8 af[4], bf[4];
#pragma unroll
    for (int mi = 0; mi < 4; ++mi)
      af[mi] = *(const short8*)(la + (wr * 64 + mi * 16 + fr) * 32 + kg);
#pragma unroll
    for (int ni = 0; ni < 4; ++ni)
      bf[ni] = *(const short8*)(lb + (wc * 64 + ni * 16 + fr) * 32 + kg);
#pragma unroll
    for (int mi = 0; mi < 4; ++mi)
#pragma unroll
      for (int ni = 0; ni < 4; ++ni)
        asm volatile("v_mfma_f32_16x16x32_bf16 %0, %1, %2, %0"
                     : "+v"(acc[mi][ni]) : "v"(af[mi]), "v"(bf[ni]));
    __syncthreads();                   // drains prefetch vmcnt + ds hazards
    cur ^= 1;
  }

  asm volatile("s_nop 7\n\ts_nop 7" ::: "memory");  // MFMA->VALU hazard guard

  const ll co = zoff(zc, z0);
  const float* bz = (flags & (F_BCOL | F_BROW)) ? bsel + zoff(zbias, zB) : nullptr;
  const int r0 = (lane >> 4) << 2;
  const int c0 = lane & 15;
#pragma unroll
  for (int mi = 0; mi < 4; ++mi) {
#pragma unroll
    for (int ni = 0; ni < 4; ++ni) {
#pragma unroll
      for (int r = 0; r < 4; ++r) {
        const int grow = bm + wr * 64 + mi * 16 + r0 + r;   // C/D row (m89)
        const int gcol = bn + wc * 64 + ni * 16 + c0;       // C/D col
        float v = acc[mi][ni][r] * scale;
        if (flags & F_BCOL) v += bz[gcol];
        if (flags & F_BROW) v += bz[grow];
        if (flags & F_RELU) v = fmaxf(v, 0.f);
        if (flags & F_RESID) v += resid[(size_t)grow * ldc + gcol];
        const ll idx = co + (ll)grow * ldc + gcol;
        if (flags & F_BF16) ((u16*)Cv)[idx] = f2b(v);
        else                ((float*)Cv)[idx] = v;
      }
    }
  }
}

// in-place softmax over rows of 1024 bf16; one wave per row, 4 rows/block
__global__ void __launch_bounds__(256)
softmax_rows(u16* __restrict__ sc)
{
  const int t = threadIdx.x, w = t >> 6, lane = t & 63;
  u16* p = sc + ((ll)blockIdx.x * 4 + w) * 1024 + lane * 16;
  short8 a = *(const short8*)p;
  short8 b = *(const short8*)(p + 8);
  float v[16];
#pragma unroll
  for (int j = 0; j < 8; ++j) { v[j] = b2f((u16)a[j]); v[8 + j] = b2f((u16)b[j]); }
  float mx = v[0];
#pragma unroll
  for (int j = 1; j < 16; ++j) mx = fmaxf(mx, v[j]);
#pragma unroll
  for (int o = 32; o >= 1; o >>= 1) mx = fmaxf(mx, __shfl_xor(mx, o));
  float s = 0.f;
#pragma unroll
  for (int j = 0; j < 16; ++j) { v[j] = __expf(v[j] - mx); s += v[j]; }
#pragma unroll
  for (int o = 32; o >= 1; o >>= 1) s += __shfl_xor(s, o);
  const float inv = 1.f / s;
  short8 oa, ob;
#pragma unroll
  for (int j = 0; j < 8; ++j) {
    oa[j] = (short)f2b(v[j] * inv);
    ob[j] = (short)f2b(v[8 + j] * inv);
  }
  *(short8*)p = oa;
  *(short8*)(p + 8) = ob;
}

// fused split-K reduce + bias + residual + LayerNorm; one wave/row, 4 rows/blk
__global__ void __launch_bounds__(256)
ln_red(const float* __restrict__ parts, int np, ll pstride,
       const float* __restrict__ bias, const float* __restrict__ resid,
       const float* __restrict__ g, const float* __restrict__ be,
       float* __restrict__ xout, u16* __restrict__ xbout)
{
  const int t = threadIdx.x, w = t >> 6, lane = t & 63;
  const ll row = (ll)blockIdx.x * 4 + w;
  const ll base = row * ND + lane * 8;
  float v[8];
  *(f32x4*)(v)     = *(const f32x4*)(resid + base);
  *(f32x4*)(v + 4) = *(const f32x4*)(resid + base + 4);
#pragma unroll
  for (int j = 0; j < 8; ++j) v[j] += bias[lane * 8 + j];
  for (int pIdx = 0; pIdx < np; ++pIdx) {
    const float* pp = parts + pIdx * pstride + base;
    f32x4 a0 = *(const f32x4*)(pp);
    f32x4 a1 = *(const f32x4*)(pp + 4);
    v[0] += a0.x; v[1] += a0.y; v[2] += a0.z; v[3] += a0.w;
    v[4] += a1.x; v[5] += a1.y; v[6] += a1.z; v[7] += a1.w;
  }
  float s = 0.f, q = 0.f;
#pragma unroll
  for (int j = 0; j < 8; ++j) { s += v[j]; q += v[j] * v[j]; }
#pragma unroll
  for (int o = 32; o >= 1; o >>= 1) { s += __shfl_xor(s, o); q += __shfl_xor(q, o); }
  const float mean = s * (1.f / ND);
  const float var  = q * (1.f / ND) - mean * mean;
  const float inv  = 1.f / sqrtf(var + 1e-5f);
#pragma unroll
  for (int j = 0; j < 8; ++j) {
    const int c = lane * 8 + j;
    const float y = (v[j] - mean) * inv * g[c] + be[c];
    xout[row * ND + c] = y;
    xbout[row * ND + c] = f2b(y);
  }
}

struct CvtJobs { const float* src[7]; u16* dst[7]; ll n[7]; };

__global__ void __launch_bounds__(256)
cvt7(CvtJobs j)
{
  const int z = blockIdx.y;
  const ll i = ((ll)blockIdx.x * 256 + threadIdx.x) * 4;
  if (i >= j.n[z]) return;
  f32x4 v = *(const f32x4*)(j.src[z] + i);
  u16x4 o;
  o.x = f2b(v.x); o.y = f2b(v.y); o.z = f2b(v.z); o.w = f2b(v.w);
  *(u16x4*)(j.dst[z] + i) = o;
}

// ---------------------------------------------------------------------------
extern "C" void kernel_launch(void* const* d_in, const int* in_sizes, int n_in,
                              void* d_out, int out_size, void* d_ws, size_t ws_size,
                              hipStream_t stream)
{
  (void)in_sizes; (void)n_in; (void)out_size; (void)ws_size;
  const float* x_in = (const float*)d_in[0];
  const float* Wq = (const float*)d_in[1];  const float* bq = (const float*)d_in[2];
  const float* Wk = (const float*)d_in[3];  const float* bk = (const float*)d_in[4];
  const float* Wv = (const float*)d_in[5];  const float* bv = (const float*)d_in[6];
  const float* Wo = (const float*)d_in[7];  const float* bo = (const float*)d_in[8];
  const float* W1 = (const float*)d_in[9];  const float* b1 = (const float*)d_in[10];
  const float* W2 = (const float*)d_in[11]; const float* b2 = (const float*)d_in[12];
  const float* ln1g = (const float*)d_in[13]; const float* ln1b = (const float*)d_in[14];
  const float* ln2g = (const float*)d_in[15]; const float* ln2b = (const float*)d_in[16];

  char* p = (char*)d_ws;
  auto alloc = [&](ll bytes) { char* r = p; p += (bytes + 255) & ~(ll)255; return r; };
  const ll nWq = (ll)NLAYER * NH * ND * ND;
  const ll nWo = (ll)NLAYER * ND * NH * ND;
  const ll nW1 = (ll)NLAYER * NDFF * ND;
  const ll nX  = (ll)NB * NS * ND;

  u16* wq_b = (u16*)alloc(nWq * 2);   // NOTE: wq_b/wk_b adjacent, qb/kb adjacent
  u16* wk_b = (u16*)alloc(nWq * 2);
  u16* wv_b = (u16*)alloc(nWq * 2);
  u16* wo_b = (u16*)alloc(nWo * 2);
  u16* w1_b = (u16*)alloc(nW1 * 2);
  u16* w2_b = (u16*)alloc(nW1 * 2);
  u16* xb   = (u16*)alloc(nX * 2);
  u16* qb   = (u16*)alloc((ll)NH * NB * NS * ND * 2);  // [h][b*s][e]
  u16* kb   = (u16*)alloc((ll)NH * NB * NS * ND * 2);
  u16* vT   = (u16*)alloc((ll)NH * NB * ND * NS * 2);  // [h][b][e][t]
  u16* scb  = (u16*)alloc((ll)NB * NH * NS * NS * 2);  // scores; overlaid by split-K parts
  u16* cat = kb;                 // overlay: k dead after scores
  u16* ffh = qb;                 // overlay: q dead after scores
  float* parts = (float*)scb;    // overlay: scb dead after heads GEMM

  CvtJobs cj;
  cj.src[0] = Wq; cj.dst[0] = wq_b; cj.n[0] = nWq;
  cj.src[1] = Wk; cj.dst[1] = wk_b; cj.n[1] = nWq;
  cj.src[2] = Wv; cj.dst[2] = wv_b; cj.n[2] = nWq;
  cj.src[3] = Wo; cj.dst[3] = wo_b; cj.n[3] = nWo;
  cj.src[4] = W1; cj.dst[4] = w1_b; cj.n[4] = nW1;
  cj.src[5] = W2; cj.dst[5] = w2_b; cj.n[5] = nW1;
  cj.src[6] = x_in; cj.dst[6] = xb; cj.n[6] = nX;
  cvt7<<<dim3((unsigned)((nWq / 4 + 255) / 256), 7), 256, 0, stream>>>(cj);

  float* xf = (float*)d_out;           // fp32 residual stream lives in d_out
  const Zm Z0{1, 0, 0};
  const ll PSTR = (ll)NB * NS * ND;    // split-K partial stride (elements)
  const int ZINF = 1 << 30;

  for (int i = 0; i < NLAYER; ++i) {
    const float* resid1 = (i == 0) ? x_in : xf;
    const ll woff = (ll)i * NH * ND * ND;

    // q+k projections merged: z in [0,16); z<8 -> Wq/bq, z>=8 -> Wk/bk.
    // C offset z*NB*NS*ND runs contiguously from qb into kb.
    gemm_bt<<<dim3(ND/128, (NB*NS)/128, 2*NH), 256, 0, stream>>>(
        xb, ND, Z0,
        wq_b + woff, ND, Zm{1, (ll)ND * ND, 0},
        wk_b + woff, bk + (ll)i * NH * ND, NH,
        qb, ND, Zm{1, (ll)NB * NS * ND, 0},
        bq + (ll)i * NH * ND, Zm{1, ND, 0}, nullptr, 1.f, ND, F_BF16 | F_BCOL);

    // vT projection (operands swapped -> transposed out): z=h*4+b, C[e][t]
    gemm_bt<<<dim3(NS/128, ND/128, NH*NB), 256, 0, stream>>>(
        wv_b + woff, ND, Zm{NB, (ll)ND * ND, 0},
        xb, ND, Zm{NB, 0, (ll)NS * ND},
        xb, nullptr, ZINF,
        vT, NS, Zm{1, (ll)ND * NS, 0},
        bv + (ll)i * NH * ND, Zm{NB, ND, 0}, nullptr, 1.f, ND, F_BF16 | F_BROW);

    // scores = q k^T / 8 : z=h*4+b
    gemm_bt<<<dim3(NS/128, NS/128, NH*NB), 256, 0, stream>>>(
        qb, ND, Zm{NB, (ll)NB * NS * ND, (ll)NS * ND},
        kb, ND, Zm{NB, (ll)NB * NS * ND, (ll)NS * ND},
        kb, nullptr, ZINF,
        scb, NS, Zm{1, (ll)NS * NS, 0},
        nullptr, Z0, nullptr, 0.125f, ND, F_BF16);

    softmax_rows<<<dim3(NB * NH * NS / 4), 256, 0, stream>>>(scb);

    // heads = attn @ v : C -> cat[b][s][h*512+e]
    gemm_bt<<<dim3(ND/128, NS/128, NH*NB), 256, 0, stream>>>(
        scb, NS, Zm{1, (ll)NS * NS, 0},
        vT, NS, Zm{1, (ll)ND * NS, 0},
        vT, nullptr, ZINF,
        cat, NH * ND, Zm{NB, (ll)ND, (ll)NS * NH * ND},
        nullptr, Z0, nullptr, 1.f, NS, F_BF16);

    // mha_out partials: split-K over K=4096 into 8 chunks of 512 (z dim)
    gemm_bt<<<dim3(ND/128, (NB*NS)/128, 8), 256, 0, stream>>>(
        cat, NH * ND, Zm{1, 512, 0},
        wo_b + (ll)i * ND * NH * ND, NH * ND, Zm{1, 512, 0},
        wo_b, nullptr, ZINF,
        parts, ND, Zm{1, PSTR, 0},
        nullptr, Z0, nullptr, 1.f, 512, 0);

    // LN1 = LayerNorm(resid + bo + sum parts)
    ln_red<<<dim3(NB * NS / 4), 256, 0, stream>>>(
        parts, 8, PSTR, bo + (ll)i * ND, resid1,
        ln1g + (ll)i * ND, ln1b + (ll)i * ND, xf, xb);

    // ffh = relu(x @ W1^T + b1)  (bf16)
    gemm_bt<<<dim3(NDFF/128, (NB*NS)/128, 1), 256, 0, stream>>>(
        xb, ND, Z0,
        w1_b + (ll)i * NDFF * ND, ND, Z0,
        w1_b, nullptr, ZINF,
        ffh, NDFF, Z0,
        b1 + (ll)i * NDFF, Z0, nullptr, 1.f, ND, F_BF16 | F_BCOL | F_RELU);

    // ff partials: split-K over K=2048 into 4 chunks of 512
    gemm_bt<<<dim3(ND/128, (NB*NS)/128, 4), 256, 0, stream>>>(
        ffh, NDFF, Zm{1, 512, 0},
        w2_b + (ll)i * ND * NDFF, NDFF, Zm{1, 512, 0},
        w2_b, nullptr, ZINF,
        parts, ND, Zm{1, PSTR, 0},
        nullptr, Z0, nullptr, 1.f, 512, 0);

    // LN2 = LayerNorm(x + b2 + sum parts)
    ln_red<<<dim3(NB * NS / 4), 256, 0, stream>>>(
        parts, 4, PSTR, b2 + (ll)i * ND, xf,
        ln2g + (ll)i * ND, ln2b + (ll)i * ND, xf, xb);
  }
}